// Round 1
// baseline (162.009 us; speedup 1.0000x reference)
//
#include <hip/hip_runtime.h>
#include <hip/hip_bf16.h>

#define NROWS 4096
#define BSZ   2048
#define DIM   128

typedef __bf16 bf16x8 __attribute__((ext_vector_type(8)));
typedef float  f32x4  __attribute__((ext_vector_type(4)));

// order-preserving float -> uint key (for atomicMin on floats)
__device__ __forceinline__ unsigned fkey(float f) {
    unsigned u = __float_as_uint(f);
    return (u & 0x80000000u) ? ~u : (u | 0x80000000u);
}
__device__ __forceinline__ float fdec(unsigned u) {
    unsigned b = (u & 0x80000000u) ? (u & 0x7FFFFFFFu) : ~u;
    return __uint_as_float(b);
}

// ---------------------------------------------------------------------------
// Kernel 1: L2-normalize each view embedding -> bf16 z [4096][128]; tile y.
// One wave per output row. 1024 blocks x 256 threads.
// ---------------------------------------------------------------------------
__global__ __launch_bounds__(256) void k_prep(const float* __restrict__ feats,
                                              const float* __restrict__ labels,
                                              __hip_bfloat16* __restrict__ zbf,
                                              float* __restrict__ y) {
    int wv   = threadIdx.x >> 6;
    int lane = threadIdx.x & 63;
    int i    = blockIdx.x * 4 + wv;          // row 0..4095
    int srow = (i < BSZ) ? i : (i - BSZ);
    int view = (i < BSZ) ? 0 : 1;
    const float* src = feats + ((size_t)srow * 2 + view) * DIM + lane * 2;
    float2 v = *reinterpret_cast<const float2*>(src);
    float ss = v.x * v.x + v.y * v.y;
    #pragma unroll
    for (int off = 32; off >= 1; off >>= 1) ss += __shfl_xor(ss, off);
    float inv = 1.0f / fmaxf(sqrtf(ss), 1e-12f);
    __hip_bfloat162 hz;
    hz.x = __float2bfloat16(v.x * inv);
    hz.y = __float2bfloat16(v.y * inv);
    ((__hip_bfloat162*)(zbf + (size_t)i * DIM))[lane] = hz;
    if (lane == 0) y[i] = labels[srow];
}

// ---------------------------------------------------------------------------
// Kernel 2: label range -> scal[1] = ymax - ymin; init scal[0] (smin key).
// ---------------------------------------------------------------------------
__global__ __launch_bounds__(256) void k_labels(const float* __restrict__ labels,
                                                float* __restrict__ scal) {
    int t = threadIdx.x;
    float mn = 1e30f, mx = -1e30f;
    for (int i = t; i < BSZ; i += 256) {
        float v = labels[i];
        mn = fminf(mn, v); mx = fmaxf(mx, v);
    }
    #pragma unroll
    for (int off = 32; off >= 1; off >>= 1) {
        mn = fminf(mn, __shfl_xor(mn, off));
        mx = fmaxf(mx, __shfl_xor(mx, off));
    }
    __shared__ float smn[4], smx[4];
    if ((t & 63) == 0) { smn[t >> 6] = mn; smx[t >> 6] = mx; }
    __syncthreads();
    if (t == 0) {
        mn = fminf(fminf(smn[0], smn[1]), fminf(smn[2], smn[3]));
        mx = fmaxf(fmaxf(smx[0], smx[1]), fmaxf(smx[2], smx[3]));
        scal[1] = mx - mn;                       // max |y_i - y_k|
        ((unsigned*)scal)[0] = 0xFFFFFFFFu;      // +inf key for atomicMin
    }
}

// ---------------------------------------------------------------------------
// Kernel 3: global min of sim = z z^T via 16x16x32 bf16 MFMA tiles.
// Grid (64,16): blockIdx.x -> 64-row panel (4 waves x 16-row strip),
// blockIdx.y -> 256-column chunk. Wave loops 16 column tiles.
// ---------------------------------------------------------------------------
__global__ __launch_bounds__(256) void k_smin(const __hip_bfloat16* __restrict__ zbf,
                                              float* __restrict__ scal) {
    int wv    = threadIdx.x >> 6;
    int lane  = threadIdx.x & 63;
    int strip = blockIdx.x * 4 + wv;     // 0..255
    int row16 = strip * 16;
    int lrow  = lane & 15;
    int lk    = lane >> 4;
    const bf16x8* zv = (const bf16x8*)zbf;   // 16 chunks of 8 bf16 per row

    bf16x8 afr[4];
    #pragma unroll
    for (int kt = 0; kt < 4; ++kt)
        afr[kt] = zv[(size_t)(row16 + lrow) * 16 + kt * 4 + lk];

    float mymin = 1e30f;
    int c0 = blockIdx.y * 256;
    for (int t = 0; t < 16; ++t) {
        int col16 = c0 + t * 16;
        bf16x8 bfr[4];
        #pragma unroll
        for (int kt = 0; kt < 4; ++kt)
            bfr[kt] = zv[(size_t)(col16 + lrow) * 16 + kt * 4 + lk];
        f32x4 acc = {0.f, 0.f, 0.f, 0.f};
        #pragma unroll
        for (int kt = 0; kt < 4; ++kt)
            acc = __builtin_amdgcn_mfma_f32_16x16x32_bf16(afr[kt], bfr[kt], acc, 0, 0, 0);
        #pragma unroll
        for (int j = 0; j < 4; ++j) mymin = fminf(mymin, acc[j]);
    }
    #pragma unroll
    for (int off = 32; off >= 1; off >>= 1)
        mymin = fminf(mymin, __shfl_xor(mymin, off));
    if (lane == 0) atomicMin((unsigned*)&scal[0], fkey(mymin));
}

// ---------------------------------------------------------------------------
// Kernel 4: main pass. Same tiling as k_smin; fused elementwise + row sums.
// Per row i accumulate: E = sum mask*exp(s/T); S1 = sum mask*w_hat;
//                       S2 = sum mask*w_hat^2*(s/T).
// C/D layout (verified): col = lane&15, row = (lane>>4)*4 + reg.
// ---------------------------------------------------------------------------
__global__ __launch_bounds__(256) void k_main(const __hip_bfloat16* __restrict__ zbf,
                                              const float* __restrict__ y,
                                              const float* __restrict__ scal,
                                              float* __restrict__ E,
                                              float* __restrict__ S1,
                                              float* __restrict__ S2) {
    int wv    = threadIdx.x >> 6;
    int lane  = threadIdx.x & 63;
    int strip = blockIdx.x * 4 + wv;
    int row16 = strip * 16;
    int lrow  = lane & 15;
    int lk    = lane >> 4;

    float smin  = fdec(((const unsigned*)scal)[0]);
    float invdz = 1.0f / ((1.0f - smin) + 1e-8f);
    float invdy = 1.0f / (scal[1] + 1e-8f);
    const float invT = 1.0f / 0.07f;

    const bf16x8* zv = (const bf16x8*)zbf;
    bf16x8 afr[4];
    #pragma unroll
    for (int kt = 0; kt < 4; ++kt)
        afr[kt] = zv[(size_t)(row16 + lrow) * 16 + kt * 4 + lk];

    int myrow0 = row16 + lk * 4;
    float yr[4];
    #pragma unroll
    for (int j = 0; j < 4; ++j) yr[j] = y[myrow0 + j];

    float accE[4] = {0.f, 0.f, 0.f, 0.f};
    float acc1[4] = {0.f, 0.f, 0.f, 0.f};
    float acc2[4] = {0.f, 0.f, 0.f, 0.f};

    int c0 = blockIdx.y * 256;
    for (int t = 0; t < 16; ++t) {
        int col16 = c0 + t * 16;
        bf16x8 bfr[4];
        #pragma unroll
        for (int kt = 0; kt < 4; ++kt)
            bfr[kt] = zv[(size_t)(col16 + lrow) * 16 + kt * 4 + lk];
        float yc = y[col16 + lrow];
        f32x4 acc = {0.f, 0.f, 0.f, 0.f};
        #pragma unroll
        for (int kt = 0; kt < 4; ++kt)
            acc = __builtin_amdgcn_mfma_f32_16x16x32_bf16(afr[kt], bfr[kt], acc, 0, 0, 0);
        int mycol = col16 + lrow;
        #pragma unroll
        for (int j = 0; j < 4; ++j) {
            float s  = acc[j];
            int   r  = myrow0 + j;
            bool  on = (r != mycol);
            float dy = yr[j] - yc;
            float w  = __expf(-2.0f * dy * dy);          // sigma=0.5 -> exp(-2 dy^2)
            float dyn = fabsf(dy) * invdy;
            float dzn = (1.0f - s) * invdz;
            float u   = fminf(fmaxf(dzn - dyn, -1.0f), 1.0f);
            float wh  = (u > 0.0f) ? (1.0f + w * u) : (1.0f - (1.0f - w) * u);
            float sT  = s * invT;
            float e   = on ? __expf(sT) : 0.0f;
            float whm = on ? wh : 0.0f;
            accE[j] += e;
            acc1[j] += whm;
            acc2[j] += whm * wh * sT;
        }
    }
    // reduce across the 16-lane group (columns of this tile strip)
    #pragma unroll
    for (int j = 0; j < 4; ++j) {
        #pragma unroll
        for (int off = 1; off < 16; off <<= 1) {
            accE[j] += __shfl_xor(accE[j], off);
            acc1[j] += __shfl_xor(acc1[j], off);
            acc2[j] += __shfl_xor(acc2[j], off);
        }
        if (lrow == 0) {
            atomicAdd(&E[myrow0 + j],  accE[j]);
            atomicAdd(&S1[myrow0 + j], acc1[j]);
            atomicAdd(&S2[myrow0 + j], acc2[j]);
        }
    }
}

// ---------------------------------------------------------------------------
// Kernel 5: finalize. loss_i = -(S2 - log(E+eps)*S1)/(S1+eps); out = mean.
// ---------------------------------------------------------------------------
__global__ __launch_bounds__(256) void k_final(const float* __restrict__ E,
                                               const float* __restrict__ S1,
                                               const float* __restrict__ S2,
                                               float* __restrict__ out) {
    int t = threadIdx.x;
    float sum = 0.f;
    for (int i = t; i < NROWS; i += 256) {
        float denom = E[i] + 1e-8f;
        float mlpp  = (S2[i] - logf(denom) * S1[i]) / (S1[i] + 1e-8f);
        sum += -mlpp;
    }
    #pragma unroll
    for (int off = 32; off >= 1; off >>= 1) sum += __shfl_xor(sum, off);
    __shared__ float red[4];
    if ((t & 63) == 0) red[t >> 6] = sum;
    __syncthreads();
    if (t == 0) out[0] = (red[0] + red[1] + red[2] + red[3]) * (1.0f / NROWS);
}

extern "C" void kernel_launch(void* const* d_in, const int* in_sizes, int n_in,
                              void* d_out, int out_size, void* d_ws, size_t ws_size,
                              hipStream_t stream) {
    const float* feats  = (const float*)d_in[0];   // (2048, 2, 128) f32
    const float* labels = (const float*)d_in[1];   // (2048, 1) f32
    float* out = (float*)d_out;

    char* ws = (char*)d_ws;
    __hip_bfloat16* zbf = (__hip_bfloat16*)ws;                  // 1 MB
    float* E    = (float*)(ws + (1 << 20));                     // 16 KB
    float* S1   = E + NROWS;
    float* S2   = S1 + NROWS;
    float* y    = S2 + NROWS;
    float* scal = y + NROWS;                                    // [0]=smin key, [1]=dymax

    hipMemsetAsync(E, 0, 3 * NROWS * sizeof(float), stream);

    k_prep  <<<NROWS / 4, 256, 0, stream>>>(feats, labels, zbf, y);
    k_labels<<<1, 256, 0, stream>>>(labels, scal);
    dim3 g(64, 16);
    k_smin  <<<g, 256, 0, stream>>>(zbf, scal);
    k_main  <<<g, 256, 0, stream>>>(zbf, y, scal, E, S1, S2);
    k_final <<<1, 256, 0, stream>>>(E, S1, S2, out);
}

// Round 2
// 134.461 us; speedup vs baseline: 1.2049x; 1.2049x over previous
//
#include <hip/hip_runtime.h>
#include <hip/hip_bf16.h>

#define NROWS 4096
#define BSZ   2048
#define DIM   128

typedef __bf16 bf16x8 __attribute__((ext_vector_type(8)));
typedef float  f32x4  __attribute__((ext_vector_type(4)));

// ---------------------------------------------------------------------------
// Kernel 1: L2-normalize each view embedding -> bf16 z [4096][128]; tile y.
// One wave per output row. 1024 blocks x 256 threads.
// ---------------------------------------------------------------------------
__global__ __launch_bounds__(256) void k_prep(const float* __restrict__ feats,
                                              const float* __restrict__ labels,
                                              __hip_bfloat16* __restrict__ zbf,
                                              float* __restrict__ y) {
    int wv   = threadIdx.x >> 6;
    int lane = threadIdx.x & 63;
    int i    = blockIdx.x * 4 + wv;          // row 0..4095
    int srow = (i < BSZ) ? i : (i - BSZ);
    int view = (i < BSZ) ? 0 : 1;
    const float* src = feats + ((size_t)srow * 2 + view) * DIM + lane * 2;
    float2 v = *reinterpret_cast<const float2*>(src);
    float ss = v.x * v.x + v.y * v.y;
    #pragma unroll
    for (int off = 32; off >= 1; off >>= 1) ss += __shfl_xor(ss, off);
    float inv = 1.0f / fmaxf(sqrtf(ss), 1e-12f);
    __hip_bfloat162 hz;
    hz.x = __float2bfloat16(v.x * inv);
    hz.y = __float2bfloat16(v.y * inv);
    ((__hip_bfloat162*)(zbf + (size_t)i * DIM))[lane] = hz;
    if (lane == 0) y[i] = labels[srow];
}

// ---------------------------------------------------------------------------
// Kernel 2: label range -> scal[1] = ymax - ymin.
// ---------------------------------------------------------------------------
__global__ __launch_bounds__(256) void k_labels(const float* __restrict__ labels,
                                                float* __restrict__ scal) {
    int t = threadIdx.x;
    float mn = 1e30f, mx = -1e30f;
    for (int i = t; i < BSZ; i += 256) {
        float v = labels[i];
        mn = fminf(mn, v); mx = fmaxf(mx, v);
    }
    #pragma unroll
    for (int off = 32; off >= 1; off >>= 1) {
        mn = fminf(mn, __shfl_xor(mn, off));
        mx = fmaxf(mx, __shfl_xor(mx, off));
    }
    __shared__ float smn[4], smx[4];
    if ((t & 63) == 0) { smn[t >> 6] = mn; smx[t >> 6] = mx; }
    __syncthreads();
    if (t == 0) {
        mn = fminf(fminf(smn[0], smn[1]), fminf(smn[2], smn[3]));
        mx = fmaxf(fmaxf(smx[0], smx[1]), fmaxf(smx[2], smx[3]));
        scal[1] = mx - mn;                       // max |y_i - y_k|
    }
}

// ---------------------------------------------------------------------------
// Kernel 3: per-block min of sim = z z^T via 16x16x32 bf16 MFMA tiles.
// Grid (64,16). NO global atomics: block min -> bmin[1024] plain store.
// ---------------------------------------------------------------------------
__global__ __launch_bounds__(256) void k_smin(const __hip_bfloat16* __restrict__ zbf,
                                              float* __restrict__ bmin) {
    int wv    = threadIdx.x >> 6;
    int lane  = threadIdx.x & 63;
    int strip = blockIdx.x * 4 + wv;     // 0..255
    int row16 = strip * 16;
    int lrow  = lane & 15;
    int lk    = lane >> 4;
    const bf16x8* zv = (const bf16x8*)zbf;   // 16 chunks of 8 bf16 per row

    bf16x8 afr[4];
    #pragma unroll
    for (int kt = 0; kt < 4; ++kt)
        afr[kt] = zv[(size_t)(row16 + lrow) * 16 + kt * 4 + lk];

    float mymin = 1e30f;
    int c0 = blockIdx.y * 256;
    for (int t = 0; t < 16; ++t) {
        int col16 = c0 + t * 16;
        bf16x8 bfr[4];
        #pragma unroll
        for (int kt = 0; kt < 4; ++kt)
            bfr[kt] = zv[(size_t)(col16 + lrow) * 16 + kt * 4 + lk];
        f32x4 acc = {0.f, 0.f, 0.f, 0.f};
        #pragma unroll
        for (int kt = 0; kt < 4; ++kt)
            acc = __builtin_amdgcn_mfma_f32_16x16x32_bf16(afr[kt], bfr[kt], acc, 0, 0, 0);
        #pragma unroll
        for (int j = 0; j < 4; ++j) mymin = fminf(mymin, acc[j]);
    }
    #pragma unroll
    for (int off = 32; off >= 1; off >>= 1)
        mymin = fminf(mymin, __shfl_xor(mymin, off));
    __shared__ float wmin[4];
    if (lane == 0) wmin[wv] = mymin;
    __syncthreads();
    if (threadIdx.x == 0)
        bmin[blockIdx.y * 64 + blockIdx.x] =
            fminf(fminf(wmin[0], wmin[1]), fminf(wmin[2], wmin[3]));
}

// ---------------------------------------------------------------------------
// Kernel 3b: reduce 1024 block minima -> scal[0] = smin (plain float).
// ---------------------------------------------------------------------------
__global__ __launch_bounds__(256) void k_redmin(const float* __restrict__ bmin,
                                                float* __restrict__ scal) {
    int t = threadIdx.x;
    float mn = 1e30f;
    #pragma unroll
    for (int c = 0; c < 4; ++c) mn = fminf(mn, bmin[c * 256 + t]);
    #pragma unroll
    for (int off = 32; off >= 1; off >>= 1) mn = fminf(mn, __shfl_xor(mn, off));
    __shared__ float wmin[4];
    if ((t & 63) == 0) wmin[t >> 6] = mn;
    __syncthreads();
    if (t == 0)
        scal[0] = fminf(fminf(wmin[0], wmin[1]), fminf(wmin[2], wmin[3]));
}

// ---------------------------------------------------------------------------
// Kernel 4: main pass. Per row i, per 256-col chunk c accumulate partials:
//   E = sum mask*exp(s/T); S1 = sum mask*w_hat; S2 = sum mask*w_hat^2*(s/T).
// Plain float4 stores to part[3][16][4096] — no atomics.
// C/D layout (verified): col = lane&15, row = (lane>>4)*4 + reg.
// ---------------------------------------------------------------------------
__global__ __launch_bounds__(256) void k_main(const __hip_bfloat16* __restrict__ zbf,
                                              const float* __restrict__ y,
                                              const float* __restrict__ scal,
                                              float* __restrict__ partE,
                                              float* __restrict__ partS1,
                                              float* __restrict__ partS2) {
    int wv    = threadIdx.x >> 6;
    int lane  = threadIdx.x & 63;
    int strip = blockIdx.x * 4 + wv;
    int row16 = strip * 16;
    int lrow  = lane & 15;
    int lk    = lane >> 4;

    float smin  = scal[0];
    float invdz = 1.0f / ((1.0f - smin) + 1e-8f);
    float invdy = 1.0f / (scal[1] + 1e-8f);
    const float invT = 1.0f / 0.07f;

    const bf16x8* zv = (const bf16x8*)zbf;
    bf16x8 afr[4];
    #pragma unroll
    for (int kt = 0; kt < 4; ++kt)
        afr[kt] = zv[(size_t)(row16 + lrow) * 16 + kt * 4 + lk];

    int myrow0 = row16 + lk * 4;
    float yr[4];
    #pragma unroll
    for (int j = 0; j < 4; ++j) yr[j] = y[myrow0 + j];

    float accE[4] = {0.f, 0.f, 0.f, 0.f};
    float acc1[4] = {0.f, 0.f, 0.f, 0.f};
    float acc2[4] = {0.f, 0.f, 0.f, 0.f};

    int c0 = blockIdx.y * 256;
    for (int t = 0; t < 16; ++t) {
        int col16 = c0 + t * 16;
        bf16x8 bfr[4];
        #pragma unroll
        for (int kt = 0; kt < 4; ++kt)
            bfr[kt] = zv[(size_t)(col16 + lrow) * 16 + kt * 4 + lk];
        float yc = y[col16 + lrow];
        f32x4 acc = {0.f, 0.f, 0.f, 0.f};
        #pragma unroll
        for (int kt = 0; kt < 4; ++kt)
            acc = __builtin_amdgcn_mfma_f32_16x16x32_bf16(afr[kt], bfr[kt], acc, 0, 0, 0);
        int mycol = col16 + lrow;
        #pragma unroll
        for (int j = 0; j < 4; ++j) {
            float s  = acc[j];
            int   r  = myrow0 + j;
            bool  on = (r != mycol);
            float dy = yr[j] - yc;
            float w  = __expf(-2.0f * dy * dy);          // sigma=0.5 -> exp(-2 dy^2)
            float dyn = fabsf(dy) * invdy;
            float dzn = (1.0f - s) * invdz;
            float u   = fminf(fmaxf(dzn - dyn, -1.0f), 1.0f);
            float wh  = (u > 0.0f) ? (1.0f + w * u) : (1.0f - (1.0f - w) * u);
            float sT  = s * invT;
            float e   = on ? __expf(sT) : 0.0f;
            float whm = on ? wh : 0.0f;
            accE[j] += e;
            acc1[j] += whm;
            acc2[j] += whm * wh * sT;
        }
    }
    // reduce across the 16-lane group (columns of this tile strip)
    #pragma unroll
    for (int j = 0; j < 4; ++j) {
        #pragma unroll
        for (int off = 1; off < 16; off <<= 1) {
            accE[j] += __shfl_xor(accE[j], off);
            acc1[j] += __shfl_xor(acc1[j], off);
            acc2[j] += __shfl_xor(acc2[j], off);
        }
    }
    if (lrow == 0) {
        size_t base = (size_t)blockIdx.y * NROWS + myrow0;
        f32x4 vE = {accE[0], accE[1], accE[2], accE[3]};
        f32x4 v1 = {acc1[0], acc1[1], acc1[2], acc1[3]};
        f32x4 v2 = {acc2[0], acc2[1], acc2[2], acc2[3]};
        *(f32x4*)&partE[base]  = vE;
        *(f32x4*)&partS1[base] = v1;
        *(f32x4*)&partS2[base] = v2;
    }
}

// ---------------------------------------------------------------------------
// Kernel 5: reduce 16 chunks per row, compute per-row loss, sum -> out.
// Grid 16 x 256: one thread per row. 16 atomicAdds total on out[0].
// ---------------------------------------------------------------------------
__global__ __launch_bounds__(256) void k_rowred(const float* __restrict__ partE,
                                                const float* __restrict__ partS1,
                                                const float* __restrict__ partS2,
                                                float* __restrict__ out) {
    int r = blockIdx.x * 256 + threadIdx.x;
    float E = 0.f, S1 = 0.f, S2 = 0.f;
    #pragma unroll
    for (int c = 0; c < 16; ++c) {
        size_t o = (size_t)c * NROWS + r;
        E  += partE[o];
        S1 += partS1[o];
        S2 += partS2[o];
    }
    float mlpp = (S2 - logf(E + 1e-8f) * S1) / (S1 + 1e-8f);
    float sum  = -mlpp;
    #pragma unroll
    for (int off = 32; off >= 1; off >>= 1) sum += __shfl_xor(sum, off);
    __shared__ float red[4];
    if ((threadIdx.x & 63) == 0) red[threadIdx.x >> 6] = sum;
    __syncthreads();
    if (threadIdx.x == 0)
        atomicAdd(out, (red[0] + red[1] + red[2] + red[3]) * (1.0f / NROWS));
}

extern "C" void kernel_launch(void* const* d_in, const int* in_sizes, int n_in,
                              void* d_out, int out_size, void* d_ws, size_t ws_size,
                              hipStream_t stream) {
    const float* feats  = (const float*)d_in[0];   // (2048, 2, 128) f32
    const float* labels = (const float*)d_in[1];   // (2048, 1) f32
    float* out = (float*)d_out;

    char* ws = (char*)d_ws;
    __hip_bfloat16* zbf = (__hip_bfloat16*)ws;                  // 1 MB
    float* y     = (float*)(ws + (1 << 20));                    // 16 KB
    float* scal  = y + NROWS;                                   // [0]=smin, [1]=dymax
    float* bmin  = scal + 16;                                   // 4 KB
    float* partE = bmin + 1024;                                 // 256 KB
    float* partS1 = partE  + 16 * NROWS;                        // 256 KB
    float* partS2 = partS1 + 16 * NROWS;                        // 256 KB

    hipMemsetAsync(out, 0, sizeof(float), stream);

    k_prep  <<<NROWS / 4, 256, 0, stream>>>(feats, labels, zbf, y);
    k_labels<<<1, 256, 0, stream>>>(labels, scal);
    dim3 g(64, 16);
    k_smin  <<<g, 256, 0, stream>>>(zbf, bmin);
    k_redmin<<<1, 256, 0, stream>>>(bmin, scal);
    k_main  <<<g, 256, 0, stream>>>(zbf, y, scal, partE, partS1, partS2);
    k_rowred<<<16, 256, 0, stream>>>(partE, partS1, partS2, out);
}

// Round 5
// 95.565 us; speedup vs baseline: 1.6953x; 1.4070x over previous
//
#include <hip/hip_runtime.h>
#include <hip/hip_bf16.h>

#define NROWS 4096
#define BSZ   2048
#define DIM   128

typedef __bf16 bf16x8 __attribute__((ext_vector_type(8)));
typedef float  f32x4  __attribute__((ext_vector_type(4)));

// ---------------------------------------------------------------------------
// Kernel 1: normalize -> bf16 z in fragment-native panel layout; y; labels.
// Panel p = 16 rows. 16B chunk index within z:
//   chunk = p*256 + kt*64 + lk*16 + lrow   (kt=k/32, lk=(k%32)/8, lrow=row%16)
// so an MFMA fragment load for panel p, k-chunk kt is zv[p*256+kt*64+lane]:
// one fully-coalesced 1KB load per wave. Block = one panel: thread t handles
// row t>>4, chunk c=t&15 (k = c*8..c*8+7). Block 0 also computes label range.
// ---------------------------------------------------------------------------
__global__ __launch_bounds__(256) void k_prep(const float* __restrict__ feats,
                                              const float* __restrict__ labels,
                                              __hip_bfloat16* __restrict__ zbf,
                                              float* __restrict__ y,
                                              float* __restrict__ scal) {
    int t = threadIdx.x;
    int p = blockIdx.x;                 // panel 0..255
    int r = t >> 4;                     // row in panel
    int c = t & 15;                     // 8-elem chunk in row
    int i = p * 16 + r;                 // global row 0..4095
    int srow = (i < BSZ) ? i : (i - BSZ);
    int view = (i < BSZ) ? 0 : 1;
    const float* src = feats + ((size_t)srow * 2 + view) * DIM + c * 8;
    float4 v0 = *reinterpret_cast<const float4*>(src);
    float4 v1 = *reinterpret_cast<const float4*>(src + 4);
    float ss = v0.x*v0.x + v0.y*v0.y + v0.z*v0.z + v0.w*v0.w
             + v1.x*v1.x + v1.y*v1.y + v1.z*v1.z + v1.w*v1.w;
    #pragma unroll
    for (int off = 8; off >= 1; off >>= 1) ss += __shfl_xor(ss, off);
    float inv = 1.0f / fmaxf(sqrtf(ss), 1e-12f);
    bf16x8 hz;
    hz[0] = (__bf16)(v0.x * inv); hz[1] = (__bf16)(v0.y * inv);
    hz[2] = (__bf16)(v0.z * inv); hz[3] = (__bf16)(v0.w * inv);
    hz[4] = (__bf16)(v1.x * inv); hz[5] = (__bf16)(v1.y * inv);
    hz[6] = (__bf16)(v1.z * inv); hz[7] = (__bf16)(v1.w * inv);
    bf16x8* zv = (bf16x8*)zbf;
    zv[(size_t)p * 256 + (c >> 2) * 64 + (c & 3) * 16 + r] = hz;
    if (c == 0) y[i] = labels[srow];

    if (p == 0) {   // label range (block 0 only)
        float mn = 1e30f, mx = -1e30f;
        for (int k = t; k < BSZ; k += 256) {
            float v = labels[k];
            mn = fminf(mn, v); mx = fmaxf(mx, v);
        }
        #pragma unroll
        for (int off = 32; off >= 1; off >>= 1) {
            mn = fminf(mn, __shfl_xor(mn, off));
            mx = fmaxf(mx, __shfl_xor(mx, off));
        }
        __shared__ float smn[4], smx[4];
        if ((t & 63) == 0) { smn[t >> 6] = mn; smx[t >> 6] = mx; }
        __syncthreads();
        if (t == 0) {
            mn = fminf(fminf(smn[0], smn[1]), fminf(smn[2], smn[3]));
            mx = fmaxf(fmaxf(smx[0], smx[1]), fmaxf(smx[2], smx[3]));
            scal[1] = mx - mn;
        }
    }
}

// ---------------------------------------------------------------------------
// Kernel 2: per-block min of sim = z z^T via 16x16x32 bf16 MFMA tiles.
// Grid (64,16). Wave strip = 16 rows x 256 cols. Block min -> bmin (no atomics).
// ---------------------------------------------------------------------------
__global__ __launch_bounds__(256) void k_smin(const __hip_bfloat16* __restrict__ zbf,
                                              float* __restrict__ bmin) {
    int wv    = threadIdx.x >> 6;
    int lane  = threadIdx.x & 63;
    int strip = blockIdx.x * 4 + wv;     // 0..255 (row panel)
    const bf16x8* zv = (const bf16x8*)zbf;

    bf16x8 afr[4];
    #pragma unroll
    for (int kt = 0; kt < 4; ++kt)
        afr[kt] = zv[(size_t)strip * 256 + kt * 64 + lane];

    float mymin = 1e30f;
    #pragma unroll
    for (int t = 0; t < 16; ++t) {
        int p = blockIdx.y * 16 + t;     // column panel
        bf16x8 bfr[4];
        #pragma unroll
        for (int kt = 0; kt < 4; ++kt)
            bfr[kt] = zv[(size_t)p * 256 + kt * 64 + lane];
        f32x4 acc = {0.f, 0.f, 0.f, 0.f};
        #pragma unroll
        for (int kt = 0; kt < 4; ++kt)
            acc = __builtin_amdgcn_mfma_f32_16x16x32_bf16(afr[kt], bfr[kt], acc, 0, 0, 0);
        #pragma unroll
        for (int j = 0; j < 4; ++j) mymin = fminf(mymin, acc[j]);
    }
    #pragma unroll
    for (int off = 32; off >= 1; off >>= 1)
        mymin = fminf(mymin, __shfl_xor(mymin, off));
    __shared__ float wmin[4];
    if (lane == 0) wmin[wv] = mymin;
    __syncthreads();
    if (threadIdx.x == 0)
        bmin[blockIdx.y * 64 + blockIdx.x] =
            fminf(fminf(wmin[0], wmin[1]), fminf(wmin[2], wmin[3]));
}

// ---------------------------------------------------------------------------
// Kernel 2b: reduce 1024 block minima -> scal[0] = smin.
// ---------------------------------------------------------------------------
__global__ __launch_bounds__(256) void k_redmin(const float* __restrict__ bmin,
                                                float* __restrict__ scal) {
    int t = threadIdx.x;
    float mn = 1e30f;
    #pragma unroll
    for (int c = 0; c < 4; ++c) mn = fminf(mn, bmin[c * 256 + t]);
    #pragma unroll
    for (int off = 32; off >= 1; off >>= 1) mn = fminf(mn, __shfl_xor(mn, off));
    __shared__ float wmin[4];
    if ((t & 63) == 0) wmin[t >> 6] = mn;
    __syncthreads();
    if (t == 0)
        scal[0] = fminf(fminf(wmin[0], wmin[1]), fminf(wmin[2], wmin[3]));
}

// ---------------------------------------------------------------------------
// Kernel 3: main pass. Recompute Gram strip (coalesced fragment loads) +
// fused elementwise; per-(chunk,row) partials (E,S1,S2), plain float4 stores.
// C/D layout (verified): col = lane&15, row = (lane>>4)*4 + reg.
// ---------------------------------------------------------------------------
__global__ __launch_bounds__(256) void k_main(const __hip_bfloat16* __restrict__ zbf,
                                              const float* __restrict__ y,
                                              const float* __restrict__ scal,
                                              float* __restrict__ partE,
                                              float* __restrict__ partS1,
                                              float* __restrict__ partS2) {
    int wv    = threadIdx.x >> 6;
    int lane  = threadIdx.x & 63;
    int strip = blockIdx.x * 4 + wv;
    int lrow  = lane & 15;
    int lk    = lane >> 4;

    float smin  = scal[0];
    float invdz = 1.0f / ((1.0f - smin) + 1e-8f);
    float invdy = 1.0f / (scal[1] + 1e-8f);
    const float invT = 1.0f / 0.07f;

    const bf16x8* zv = (const bf16x8*)zbf;
    bf16x8 afr[4];
    #pragma unroll
    for (int kt = 0; kt < 4; ++kt)
        afr[kt] = zv[(size_t)strip * 256 + kt * 64 + lane];

    int myrow0 = strip * 16 + lk * 4;
    float yr[4];
    #pragma unroll
    for (int j = 0; j < 4; ++j) yr[j] = y[myrow0 + j];

    float accE[4] = {0.f, 0.f, 0.f, 0.f};
    float acc1[4] = {0.f, 0.f, 0.f, 0.f};
    float acc2[4] = {0.f, 0.f, 0.f, 0.f};

    int c0 = blockIdx.y * 256;
    #pragma unroll
    for (int t = 0; t < 16; ++t) {
        int p = blockIdx.y * 16 + t;
        bf16x8 bfr[4];
        #pragma unroll
        for (int kt = 0; kt < 4; ++kt)
            bfr[kt] = zv[(size_t)p * 256 + kt * 64 + lane];
        float yc = y[c0 + t * 16 + lrow];
        f32x4 acc = {0.f, 0.f, 0.f, 0.f};
        #pragma unroll
        for (int kt = 0; kt < 4; ++kt)
            acc = __builtin_amdgcn_mfma_f32_16x16x32_bf16(afr[kt], bfr[kt], acc, 0, 0, 0);
        int mycol = c0 + t * 16 + lrow;
        #pragma unroll
        for (int j = 0; j < 4; ++j) {
            float s  = acc[j];
            bool  on = (myrow0 + j != mycol);
            float dy = yr[j] - yc;
            float w  = __expf(-2.0f * dy * dy);          // sigma=0.5
            float dyn = fabsf(dy) * invdy;
            float dzn = (1.0f - s) * invdz;
            float u   = fminf(fmaxf(dzn - dyn, -1.0f), 1.0f);
            float wh  = (u > 0.0f) ? (1.0f + w * u) : (1.0f - (1.0f - w) * u);
            float sT  = s * invT;
            float e   = on ? __expf(sT) : 0.0f;
            float whm = on ? wh : 0.0f;
            accE[j] += e;
            acc1[j] += whm;
            acc2[j] += whm * wh * sT;
        }
    }
    #pragma unroll
    for (int j = 0; j < 4; ++j) {
        #pragma unroll
        for (int off = 1; off < 16; off <<= 1) {
            accE[j] += __shfl_xor(accE[j], off);
            acc1[j] += __shfl_xor(acc1[j], off);
            acc2[j] += __shfl_xor(acc2[j], off);
        }
    }
    if (lrow == 0) {
        size_t base = (size_t)blockIdx.y * NROWS + myrow0;
        f32x4 vE = {accE[0], accE[1], accE[2], accE[3]};
        f32x4 v1 = {acc1[0], acc1[1], acc1[2], acc1[3]};
        f32x4 v2 = {acc2[0], acc2[1], acc2[2], acc2[3]};
        *(f32x4*)&partE[base]  = vE;
        *(f32x4*)&partS1[base] = v1;
        *(f32x4*)&partS2[base] = v2;
    }
}

// ---------------------------------------------------------------------------
// Kernel 4: reduce 16 chunks per row, per-row loss, sum -> out (16 atomics).
// ---------------------------------------------------------------------------
__global__ __launch_bounds__(256) void k_rowred(const float* __restrict__ partE,
                                                const float* __restrict__ partS1,
                                                const float* __restrict__ partS2,
                                                float* __restrict__ out) {
    int r = blockIdx.x * 256 + threadIdx.x;
    float E = 0.f, S1 = 0.f, S2 = 0.f;
    #pragma unroll
    for (int c = 0; c < 16; ++c) {
        size_t o = (size_t)c * NROWS + r;
        E  += partE[o];
        S1 += partS1[o];
        S2 += partS2[o];
    }
    float mlpp = (S2 - logf(E + 1e-8f) * S1) / (S1 + 1e-8f);
    float sum  = -mlpp;
    #pragma unroll
    for (int off = 32; off >= 1; off >>= 1) sum += __shfl_xor(sum, off);
    __shared__ float red[4];
    if ((threadIdx.x & 63) == 0) red[threadIdx.x >> 6] = sum;
    __syncthreads();
    if (threadIdx.x == 0)
        atomicAdd(out, (red[0] + red[1] + red[2] + red[3]) * (1.0f / NROWS));
}

extern "C" void kernel_launch(void* const* d_in, const int* in_sizes, int n_in,
                              void* d_out, int out_size, void* d_ws, size_t ws_size,
                              hipStream_t stream) {
    const float* feats  = (const float*)d_in[0];   // (2048, 2, 128) f32
    const float* labels = (const float*)d_in[1];   // (2048, 1) f32
    float* out = (float*)d_out;

    char* ws = (char*)d_ws;
    __hip_bfloat16* zbf = (__hip_bfloat16*)ws;                  // 1 MB
    float* y      = (float*)(ws + (1 << 20));                   // 16 KB
    float* scal   = y + NROWS;
    float* bmin   = scal + 16;                                  // 4 KB
    float* partE  = bmin + 1024;                                // 256 KB
    float* partS1 = partE  + 16 * NROWS;
    float* partS2 = partS1 + 16 * NROWS;

    hipMemsetAsync(out, 0, sizeof(float), stream);

    k_prep  <<<NROWS / 16, 256, 0, stream>>>(feats, labels, zbf, y, scal);
    dim3 g(64, 16);
    k_smin  <<<g, 256, 0, stream>>>(zbf, bmin);
    k_redmin<<<1, 256, 0, stream>>>(bmin, scal);
    k_main  <<<g, 256, 0, stream>>>(zbf, y, scal, partE, partS1, partS2);
    k_rowred<<<16, 256, 0, stream>>>(partE, partS1, partS2, out);
}